// Round 2
// baseline (83.501 us; speedup 1.0000x reference)
//
#include <hip/hip_runtime.h>
#include <hip/hip_fp16.h>

// Problem constants (from reference setup_inputs)
#define NH 4       // heads
#define NQ 64      // queries
#define NK 64      // index dim
#define NI 2048    // items
#define ND 128     // d_model
#define NHI (NH * NI)              // 8192 flat score columns per query
#define REC_ELEMS ((size_t)NQ * NHI * ND)  // 67108864 floats, output 0

// ---------------------------------------------------------------------------
// Kernel A: score[q][h*NI + i] = f32( f16( sum_k f32(f16(query)) * f32(f16(index)) ) )
// One block per (h, q) pair; 256 threads each handle NI/256 = 8 items.
// Accumulation: single sequential f32 chain, contraction OFF, to bit-match
// numpy's HALF matmul (f32 accumulate, separate mul+add, final f16 round).
// ---------------------------------------------------------------------------
__global__ __launch_bounds__(256) void score_kernel(
    const float* __restrict__ query,   // (NH, NQ, NK)
    const float* __restrict__ index,   // (NI, NK)
    float* __restrict__ score_out) {   // (NQ, NHI)
#pragma clang fp contract(off)
  const int hq = blockIdx.x;           // [0, NH*NQ)
  const int h  = hq >> 6;              // / NQ
  const int qq = hq & 63;              // % NQ

  __shared__ float qs[NK];
  const int t = threadIdx.x;
  if (t < NK) {
    float v = query[((size_t)(h * NQ + qq)) * NK + t];
    qs[t] = __half2float(__float2half(v));   // fp16-round the query once
  }
  __syncthreads();

  for (int i = t; i < NI; i += 256) {
    const float4* row4 = (const float4*)(index + (size_t)i * NK);
    float acc = 0.0f;
    for (int k4 = 0; k4 < NK / 4; ++k4) {
      float4 v = row4[k4];
      // keep a single sequential dependence chain (numpy HALF_dot order)
      acc = acc + qs[k4 * 4 + 0] * __half2float(__float2half(v.x));
      acc = acc + qs[k4 * 4 + 1] * __half2float(__float2half(v.y));
      acc = acc + qs[k4 * 4 + 2] * __half2float(__float2half(v.z));
      acc = acc + qs[k4 * 4 + 3] * __half2float(__float2half(v.w));
    }
    float s = __half2float(__float2half(acc));  // final f16 rounding (matmul output dtype)
    score_out[(size_t)qq * NHI + (size_t)h * NI + i] = s;
  }
}

// ---------------------------------------------------------------------------
// Kernel B: per query row, stable compaction of passing flat indices.
// One block (256 threads) per q; each thread owns 32 consecutive columns.
// Hillis-Steele scan of per-thread counts in LDS.
// ---------------------------------------------------------------------------
__global__ __launch_bounds__(256) void compact_kernel(
    const float* __restrict__ score,   // (NQ, NHI)
    int* __restrict__ comp,            // (NQ, NHI) compacted indices
    int* __restrict__ npass) {         // (NQ)
  const int q = blockIdx.x;
  const int t = threadIdx.x;
  const float* srow = score + (size_t)q * NHI;
  const int base = t * 32;

  int cnt = 0;
  for (int j = 0; j < 32; ++j) cnt += (srow[base + j] > 0.1f) ? 1 : 0;

  __shared__ int cs[256];
  cs[t] = cnt;
  __syncthreads();
  for (int off = 1; off < 256; off <<= 1) {
    int v = (t >= off) ? cs[t - off] : 0;
    __syncthreads();
    cs[t] += v;
    __syncthreads();
  }
  int pos = cs[t] - cnt;  // exclusive prefix
  int* crow = comp + (size_t)q * NHI;
  for (int j = 0; j < 32; ++j) {
    if (srow[base + j] > 0.1f) crow[pos++] = base + j;
  }
  if (t == 255) npass[q] = cs[255];
}

// ---------------------------------------------------------------------------
// Kernel C: the big write. out[q][p][:] = score[q][comp[q][p]] * record[j % NI][:]
// for p < npass[q], else zeros. One wave handles a PAIR of rows: 64 lanes,
// 32 lanes per row, float4 per lane (row = 128 f32 = 32 x float4 = 512 B).
// ---------------------------------------------------------------------------
__global__ __launch_bounds__(256) void write_kernel(
    const float* __restrict__ score,   // (NQ, NHI)
    const float* __restrict__ record,  // (NI, ND)
    const int* __restrict__ comp,      // (NQ, NHI)
    const int* __restrict__ npass,     // (NQ)
    float* __restrict__ out) {         // (NQ, NHI, ND)
  const int lane = threadIdx.x & 63;
  const int half = lane >> 5;   // which row of the pair
  const int l32  = lane & 31;   // float4 slot within the row
  const long wave   = (long)blockIdx.x * (blockDim.x >> 6) + (threadIdx.x >> 6);
  const long nwaves = (long)gridDim.x * (blockDim.x >> 6);
  const long npairs = (long)NQ * NHI / 2;  // 262144

  for (long pr = wave; pr < npairs; pr += nwaves) {
    const long r = pr * 2 + half;          // output row in [0, NQ*NHI)
    const int q = (int)(r >> 13);          // / NHI
    const int p = (int)(r & (NHI - 1));    // % NHI
    float4 val = make_float4(0.f, 0.f, 0.f, 0.f);
    if (p < npass[q]) {
      const int j = comp[r];
      const float s = score[((size_t)q << 13) + j];
      const float4* rec = (const float4*)(record + ((size_t)(j & (NI - 1)) << 7));
      float4 rv = rec[l32];
      val = make_float4(s * rv.x, s * rv.y, s * rv.z, s * rv.w);
    }
    ((float4*)(out + ((size_t)r << 7)))[l32] = val;
  }
}

// ---------------------------------------------------------------------------
extern "C" void kernel_launch(void* const* d_in, const int* in_sizes, int n_in,
                              void* d_out, int out_size, void* d_ws, size_t ws_size,
                              hipStream_t stream) {
  const float* query  = (const float*)d_in[0];  // (NH, NQ, NK)
  const float* record = (const float*)d_in[1];  // (NI, ND)
  const float* index  = (const float*)d_in[2];  // (NI, NK)

  float* out       = (float*)d_out;
  float* score_out = out + REC_ELEMS;           // output 1 region: (NQ, NHI)

  int* comp  = (int*)d_ws;                      // (NQ, NHI) ints = 2 MiB
  int* npass = comp + (size_t)NQ * NHI;         // (NQ) ints

  score_kernel<<<NH * NQ, 256, 0, stream>>>(query, index, score_out);
  compact_kernel<<<NQ, 256, 0, stream>>>(score_out, comp, npass);
  write_kernel<<<2048, 256, 0, stream>>>(score_out, record, comp, npass, out);
}